// Round 8
// baseline (324.304 us; speedup 1.0000x reference)
//
#include <hip/hip_runtime.h>
#include <stdint.h>

// ---------- types ----------
typedef __bf16 bf16x8 __attribute__((ext_vector_type(8)));
typedef float f32x4 __attribute__((ext_vector_type(4)));
typedef unsigned short us8_t __attribute__((ext_vector_type(8)));

__device__ __forceinline__ unsigned short f2bf(float f) {
  __bf16 b = (__bf16)f;
  return __builtin_bit_cast(unsigned short, b);
}
__device__ __forceinline__ float bf2f(unsigned short u) {
  union { uint32_t u; float f; } v; v.u = ((uint32_t)u) << 16;
  return v.f;
}

// async global->LDS, 16B per lane (wave-uniform LDS base + lane*16)
__device__ __forceinline__ void gload16(const void* g, void* l) {
  __builtin_amdgcn_global_load_lds(
      (const __attribute__((address_space(1))) void*)g,
      (__attribute__((address_space(3))) void*)l, 16, 0, 0);
}

// Stage a 128x32-short bf16 tile (linear [128][32] LDS) via 2 gload16/wave.
__device__ __forceinline__ void stage_tile(const unsigned short* g, size_t ldg,
                                           unsigned short* lds, int wid, int lane) {
#pragma unroll
  for (int i = 0; i < 2; ++i) {
    int seg = wid * 2 + i;  // 0..7, 16 rows each
    const unsigned short* gp = g + (size_t)(seg * 16 + (lane >> 2)) * ldg + (lane & 3) * 8;
    gload16(gp, lds + seg * 512);
  }
}

// 16 MFMA on a staged tile pair. A stride fixed 32 shorts; B stride param.
__device__ __forceinline__ void mfma_step(const unsigned short* As, const unsigned short* Bs,
                                          int ldb, f32x4 (*acc)[4],
                                          int wr, int wc, int lr, int lk) {
  bf16x8 a[4], b[4];
#pragma unroll
  for (int mi = 0; mi < 4; ++mi)
    a[mi] = *(const bf16x8*)(As + (wr + mi * 16 + lr) * 32 + lk * 8);
#pragma unroll
  for (int ni = 0; ni < 4; ++ni)
    b[ni] = *(const bf16x8*)(Bs + (wc + ni * 16 + lr) * ldb + lk * 8);
#pragma unroll
  for (int mi = 0; mi < 4; ++mi)
#pragma unroll
    for (int ni = 0; ni < 4; ++ni)
      acc[mi][ni] = __builtin_amdgcn_mfma_f32_16x16x32_bf16(a[mi], b[ni], acc[mi][ni], 0, 0, 0);
}

// =====================================================================
// Convert x (16.7M f32) and W (0.52M f32) to bf16 (into out region).
// =====================================================================
__global__ __launch_bounds__(256) void k_convert(
    const float* __restrict__ X, const float* __restrict__ W,
    unsigned short* __restrict__ Xb, unsigned short* __restrict__ Wb) {
  const size_t idx = (size_t)blockIdx.x * 256 + threadIdx.x;
  const size_t stride = (size_t)gridDim.x * 256;
  for (size_t i = idx; i < (size_t)16777216 / 8; i += stride) {
    float4 f0 = ((const float4*)X)[2 * i], f1 = ((const float4*)X)[2 * i + 1];
    us8_t w = { f2bf(f0.x), f2bf(f0.y), f2bf(f0.z), f2bf(f0.w),
                f2bf(f1.x), f2bf(f1.y), f2bf(f1.z), f2bf(f1.w) };
    ((us8_t*)Xb)[i] = w;
  }
  for (size_t i = idx; i < (size_t)524288 / 8; i += stride) {
    float4 f0 = ((const float4*)W)[2 * i], f1 = ((const float4*)W)[2 * i + 1];
    us8_t w = { f2bf(f0.x), f2bf(f0.y), f2bf(f0.z), f2bf(f0.w),
                f2bf(f1.x), f2bf(f1.y), f2bf(f1.z), f2bf(f1.w) };
    ((us8_t*)Wb)[i] = w;
  }
}

// =====================================================================
// Convert A (33.5M f32) to bf16 Ab (runs after gemm1; Ab in out region).
// =====================================================================
__global__ __launch_bounds__(256) void k_convertA(
    const float* __restrict__ A, unsigned short* __restrict__ Ab) {
  const size_t idx = (size_t)blockIdx.x * 256 + threadIdx.x;
  const size_t stride = (size_t)gridDim.x * 256;
  for (size_t i = idx; i < (size_t)33554432 / 8; i += stride) {
    float4 f0 = ((const float4*)A)[2 * i], f1 = ((const float4*)A)[2 * i + 1];
    us8_t w = { f2bf(f0.x), f2bf(f0.y), f2bf(f0.z), f2bf(f0.w),
                f2bf(f1.x), f2bf(f1.y), f2bf(f1.z), f2bf(f1.w) };
    ((us8_t*)Ab)[i] = w;
  }
}

// =====================================================================
// Stage 1: h[n,o,v] = sum_c W[o,c]*x[n,v,c] + b[o]  (bf16 out, raw h)
// 2-phase pipeline: stage tile t+1 under compute of tile t, 1 barrier/step.
// =====================================================================
__global__ __launch_bounds__(256) void k_gemm1(
    const unsigned short* __restrict__ Wb, const unsigned short* __restrict__ Xb,
    const float* __restrict__ convb, unsigned short* __restrict__ H) {
  __shared__ unsigned short A0[4096], B0[4096], A1[4096], B1[4096];
  const int tid = threadIdx.x;
  const int L = blockIdx.x;
  const int xcd = L & 7, slot = L >> 3;
  const int n = xcd * 8 + (slot >> 5);
  const int tile = slot & 31;
  const int tm = tile >> 2, tn = tile & 3;
  const unsigned short* gA = Wb + (size_t)tm * 128 * 512;
  const unsigned short* gB = Xb + ((size_t)n * 512 + tn * 128) * 512;
  const int lane = tid & 63, wid = tid >> 6;
  const int wr = (wid >> 1) * 64, wc = (wid & 1) * 64;
  const int lr = lane & 15, lk = lane >> 4;
  f32x4 acc[4][4] = {};
  stage_tile(gA, 512, A0, wid, lane);
  stage_tile(gB, 512, B0, wid, lane);
  for (int k0 = 0; k0 < 512; k0 += 64) {
    __syncthreads();  // drains DMA for {A0,B0}; closes prior reads of {A1,B1}
    stage_tile(gA + k0 + 32, 512, A1, wid, lane);
    stage_tile(gB + k0 + 32, 512, B1, wid, lane);
    mfma_step(A0, B0, 32, acc, wr, wc, lr, lk);
    __syncthreads();  // drains DMA for {A1,B1}; closes reads of {A0,B0}
    if (k0 + 64 < 512) {
      stage_tile(gA + k0 + 64, 512, A0, wid, lane);
      stage_tile(gB + k0 + 64, 512, B0, wid, lane);
    }
    mfma_step(A1, B1, 32, acc, wr, wc, lr, lk);
  }
  unsigned short* Hn = H + (size_t)n * 1024 * 512;
#pragma unroll
  for (int mi = 0; mi < 4; ++mi)
#pragma unroll
    for (int i = 0; i < 4; ++i) {
      int o = tm * 128 + wr + mi * 16 + lk * 4 + i;
      float bias = convb[o];
#pragma unroll
      for (int ni = 0; ni < 4; ++ni) {
        int v = tn * 128 + wc + ni * 16 + lr;
        Hn[(size_t)o * 512 + v] = f2bf(acc[mi][ni][i] + bias);
      }
    }
}

// =====================================================================
// BN stats from raw H -> scale/shift (separate pass; 67 MB read ~14 us)
// =====================================================================
__global__ __launch_bounds__(256) void k_bn(
    const unsigned short* __restrict__ H, const float* __restrict__ gamma,
    const float* __restrict__ beta, float* __restrict__ sc_sh) {
  const int o = blockIdx.x;
  const int tid = threadIdx.x;
  const int g = tid >> 6, l = tid & 63;
  float s1 = 0.f, s2 = 0.f;
  for (int step = 0; step < 16; ++step) {
    int n = g + step * 4;
    const us8_t* row = (const us8_t*)(H + ((size_t)n * 1024 + o) * 512);
    us8_t v = row[l];
#pragma unroll
    for (int j = 0; j < 8; ++j) { float f = bf2f(v[j]); s1 += f; s2 += f * f; }
  }
  __shared__ float r1[256], r2[256];
  r1[tid] = s1; r2[tid] = s2;
  __syncthreads();
  for (int off = 128; off > 0; off >>= 1) {
    if (tid < off) { r1[tid] += r1[tid + off]; r2[tid] += r2[tid + off]; }
    __syncthreads();
  }
  if (tid == 0) {
    float mean = r1[0] * (1.0f / 32768.0f);
    float var = r2[0] * (1.0f / 32768.0f) - mean * mean;
    float s = gamma[o] * rsqrtf(var + 1e-5f);
    sc_sh[o] = s;
    sc_sh[1024 + o] = beta[o] - mean * s;
  }
}

// =====================================================================
// Fallback only (ws too small): in-place affine on H.
// =====================================================================
__global__ __launch_bounds__(256) void k_affine(
    unsigned short* __restrict__ H, const float* __restrict__ sc_sh) {
  const size_t idx = (size_t)blockIdx.x * 256 + threadIdx.x;
  const size_t stride = (size_t)gridDim.x * 256;
  const size_t total8 = (size_t)64 * 1024 * 512 / 8;
  for (size_t i = idx; i < total8; i += stride) {
    size_t base = i * 8;
    int o = (int)((base >> 9) & 1023);
    float sc = sc_sh[o], sh = sc_sh[1024 + o];
    us8_t v = ((const us8_t*)H)[i];
    us8_t w;
#pragma unroll
    for (int j = 0; j < 8; ++j) w[j] = f2bf(fmaf(bf2f(v[j]), sc, sh));
    ((us8_t*)H)[i] = w;
  }
}

// =====================================================================
// Stage 2': B2[nk][m,m'] = sum_e Ab[m,e]*Ab[m',e]  (2-phase bf16)
// =====================================================================
__global__ __launch_bounds__(256) void k_aat(
    const unsigned short* __restrict__ Ab, unsigned short* __restrict__ B2) {
  __shared__ unsigned short A0[4096], B0[4096], A1[4096], B1[4096];
  const int tid = threadIdx.x;
  const int L = blockIdx.x;
  const int xcd = L & 7, slot = L >> 3;
  const int nk = xcd * 16 + (slot >> 4);
  const int tile = slot & 15;
  const int tm = tile >> 2, tn = tile & 3;
  const unsigned short* Ank = Ab + (size_t)nk * 262144;
  const unsigned short* gA = Ank + (size_t)tm * 128 * 512;
  const unsigned short* gB = Ank + (size_t)tn * 128 * 512;
  const int lane = tid & 63, wid = tid >> 6;
  const int wr = (wid >> 1) * 64, wc = (wid & 1) * 64;
  const int lr = lane & 15, lk = lane >> 4;
  f32x4 acc[4][4] = {};
  stage_tile(gA, 512, A0, wid, lane);
  stage_tile(gB, 512, B0, wid, lane);
  for (int k0 = 0; k0 < 512; k0 += 64) {
    __syncthreads();
    stage_tile(gA + k0 + 32, 512, A1, wid, lane);
    stage_tile(gB + k0 + 32, 512, B1, wid, lane);
    mfma_step(A0, B0, 32, acc, wr, wc, lr, lk);
    __syncthreads();
    if (k0 + 64 < 512) {
      stage_tile(gA + k0 + 64, 512, A0, wid, lane);
      stage_tile(gB + k0 + 64, 512, B0, wid, lane);
    }
    mfma_step(A1, B1, 32, acc, wr, wc, lr, lk);
  }
  unsigned short* Bn = B2 + (size_t)nk * 262144;
#pragma unroll
  for (int mi = 0; mi < 4; ++mi)
#pragma unroll
    for (int i = 0; i < 4; ++i) {
      int m = tm * 128 + wr + mi * 16 + lk * 4 + i;
#pragma unroll
      for (int ni = 0; ni < 4; ++ni) {
        int mp = tn * 128 + wc + ni * 16 + lr;
        Bn[(size_t)m * 512 + mp] = f2bf(acc[mi][ni][i]);
      }
    }
}

// ---- gemm3 helpers: reg-staged B tile (issue-early / write-late) ----
__device__ __forceinline__ void ldB(const unsigned short* gB, int k, int tid,
                                    us8_t* va, us8_t* vb) {
  int r0 = tid >> 2, c8 = (tid & 3) * 8;
  *va = *(const us8_t*)(gB + (size_t)r0 * 512 + k + c8);
  *vb = *(const us8_t*)(gB + (size_t)(r0 + 64) * 512 + k + c8);
}

template <bool AFFINE>
__device__ __forceinline__ void wrB(unsigned short* Bs, us8_t va, us8_t vb,
                                    float scA, float shA, float scB, float shB,
                                    int tid) {
  int r0 = tid >> 2, c8 = (tid & 3) * 8;
  us8_t w;
  if (AFFINE) {
#pragma unroll
    for (int j = 0; j < 8; ++j) w[j] = f2bf(fmaf(bf2f(va[j]), scA, shA));
  } else w = va;
  *(us8_t*)&Bs[r0 * 40 + c8] = w;
  if (AFFINE) {
#pragma unroll
    for (int j = 0; j < 8; ++j) w[j] = f2bf(fmaf(bf2f(vb[j]), scB, shB));
  } else w = vb;
  *(us8_t*)&Bs[(r0 + 64) * 40 + c8] = w;
}

// =====================================================================
// Stage 3': out[n,v,c] = (1+eps)*x + sum_kk sum_m' B2[nk][v,m'] * h'[o,m']
// A-op via 2-phase global_load_lds; B-op reg-staged with affine folded,
// loads issued one tile early (overlap with MFMA), ds_write just-in-time.
// =====================================================================
template <bool AFFINE>
__global__ __launch_bounds__(256) void k_gemm3(
    const unsigned short* __restrict__ B2, const unsigned short* __restrict__ H,
    const float* __restrict__ sc_sh, const float* __restrict__ X,
    const float* __restrict__ epsp, float* __restrict__ out) {
  __shared__ unsigned short A0[4096], A1[4096];
  __shared__ unsigned short Bs0[128 * 40], Bs1[128 * 40];
  const int tid = threadIdx.x;
  const int L = blockIdx.x;
  const int xcd = L & 7, slot = L >> 3;
  const int n = xcd * 8 + (slot >> 4);
  const int tile = slot & 15;
  const int tm = tile >> 2, tn = tile & 3;
  const int lane = tid & 63, wid = tid >> 6;
  const int wr = (wid >> 1) * 64, wc = (wid & 1) * 64;
  const int lr = lane & 15, lk = lane >> 4;
  f32x4 acc[4][4] = {};
  for (int kk = 0; kk < 2; ++kk) {
    const unsigned short* gA = B2 + ((size_t)(n * 2 + kk) * 512 + tm * 128) * 512;
    const unsigned short* gB = H + ((size_t)n * 1024 + kk * 512 + tn * 128) * 512;
    float scA = 0.f, shA = 0.f, scB = 0.f, shB = 0.f;
    if (AFFINE) {
      int r0 = tid >> 2;
      int ch = kk * 512 + tn * 128;
      scA = sc_sh[ch + r0];       shA = sc_sh[1024 + ch + r0];
      scB = sc_sh[ch + r0 + 64];  shB = sc_sh[1024 + ch + r0 + 64];
    }
    us8_t va, vb;
    ldB(gB, 0, tid, &va, &vb);
    stage_tile(gA, 512, A0, wid, lane);
    wrB<AFFINE>(Bs0, va, vb, scA, shA, scB, shB, tid);
    for (int k0 = 0; k0 < 512; k0 += 64) {
      __syncthreads();  // {A0,Bs0} ready; prior reads of {A1,Bs1} closed
      stage_tile(gA + k0 + 32, 512, A1, wid, lane);
      ldB(gB, k0 + 32, tid, &va, &vb);
      mfma_step(A0, Bs0, 40, acc, wr, wc, lr, lk);
      wrB<AFFINE>(Bs1, va, vb, scA, shA, scB, shB, tid);
      __syncthreads();  // {A1,Bs1} ready; reads of {A0,Bs0} closed
      const bool more = (k0 + 64 < 512);
      if (more) {
        stage_tile(gA + k0 + 64, 512, A0, wid, lane);
        ldB(gB, k0 + 64, tid, &va, &vb);
      }
      mfma_step(A1, Bs1, 40, acc, wr, wc, lr, lk);
      if (more) wrB<AFFINE>(Bs0, va, vb, scA, shA, scB, shB, tid);
    }
    // kk transition: prologue writes {A0,Bs0}; any lagging wave is past the
    // mid-iteration barrier (reads {A1,Bs1} only) -> no conflict.
  }
  const float e1 = 1.0f + epsp[0];
#pragma unroll
  for (int mi = 0; mi < 4; ++mi)
#pragma unroll
    for (int i = 0; i < 4; ++i) {
      int v = tm * 128 + wr + mi * 16 + lk * 4 + i;
#pragma unroll
      for (int ni = 0; ni < 4; ++ni) {
        int c = tn * 128 + wc + ni * 16 + lr;
        size_t idx = ((size_t)n * 512 + v) * 512 + c;
        out[idx] = fmaf(e1, X[idx], acc[mi][ni][i]);
      }
    }
}

// =====================================================================
// At[nk,e,m] = A[nk,m,e]  (runs LAST) — 64x64 float4 tiles
// =====================================================================
__global__ __launch_bounds__(256) void k_at(
    const float* __restrict__ A, float* __restrict__ At) {
  __shared__ float tile[64][65];
  const int nk = blockIdx.z;
  const int e0 = blockIdx.x * 64, m0 = blockIdx.y * 64;
  const float* src = A + (size_t)nk * 262144;
  float* dst = At + (size_t)nk * 262144;
  const int t = threadIdx.x;
#pragma unroll
  for (int j = 0; j < 4; ++j) {
    int ch = t + j * 256;
    int r = ch >> 4, c4 = (ch & 15) * 4;
    float4 f = *(const float4*)(src + (size_t)(m0 + r) * 512 + e0 + c4);
    tile[r][c4] = f.x; tile[r][c4 + 1] = f.y; tile[r][c4 + 2] = f.z; tile[r][c4 + 3] = f.w;
  }
  __syncthreads();
#pragma unroll
  for (int j = 0; j < 4; ++j) {
    int ch = t + j * 256;
    int e = ch >> 4, m4 = (ch & 15) * 4;
    float4 g = { tile[m4][e], tile[m4 + 1][e], tile[m4 + 2][e], tile[m4 + 3][e] };
    *(float4*)(dst + (size_t)(e0 + e) * 512 + m0 + m4) = g;
  }
}

// =====================================================================
extern "C" void kernel_launch(void* const* d_in, const int* in_sizes, int n_in,
                              void* d_out, int out_size, void* d_ws, size_t ws_size,
                              hipStream_t stream) {
  const float* x      = (const float*)d_in[0];  // (64,512,512)
  const float* A      = (const float*)d_in[1];  // (64,2,512,512)
  const float* conv_w = (const float*)d_in[2];  // (1024,512)
  const float* conv_b = (const float*)d_in[3];  // (1024,)
  const float* gamma  = (const float*)d_in[4];  // (1024,)
  const float* beta   = (const float*)d_in[5];  // (1024,)
  const float* eps_p  = (const float*)d_in[6];  // (1,)

  float* out = (float*)d_out;           // 16,777,216 floats (67 MB)
  float* At  = out + (size_t)16777216;  // 33,554,432 floats (134 MB)

  // Scratch (inside d_out; every byte dead before its region's final write):
  //   At region: B2 bf16 [0..33.5M shorts) | H bf16 [33.5M..67M shorts)
  //   out region timeline: {Xb|Wb} -> (gemm1 consumes) -> {Ab} -> (gemm3 overwrites)
  unsigned short* B2 = (unsigned short*)At;
  unsigned short* H  = (unsigned short*)(At + (size_t)16777216);
  unsigned short* Xb = (unsigned short*)out;
  unsigned short* Wb = Xb + (size_t)16777216;
  unsigned short* Ab = (unsigned short*)out;  // 33.5M shorts = exact out-region fit

  float* wsf = (float*)d_ws;

  if (ws_size >= 8192) {
    float* sc_sh = wsf;
    k_convert    <<<2048, 256, 0, stream>>>(x, conv_w, Xb, Wb);
    k_gemm1      <<<2048, 256, 0, stream>>>(Wb, Xb, conv_b, H);
    k_bn         <<<1024, 256, 0, stream>>>(H, gamma, beta, sc_sh);
    k_convertA   <<<2048, 256, 0, stream>>>(A, Ab);
    k_aat        <<<2048, 256, 0, stream>>>(Ab, B2);
    k_gemm3<true><<<1024, 256, 0, stream>>>(B2, H, sc_sh, x, eps_p, out);
  } else {
    // sc_sh in dead Xb space; affine applied before convertA overwrites it.
    float* sc_sh = out;
    k_convert     <<<2048, 256, 0, stream>>>(x, conv_w, Xb, Wb);
    k_gemm1       <<<2048, 256, 0, stream>>>(Wb, Xb, conv_b, H);
    k_bn          <<<1024, 256, 0, stream>>>(H, gamma, beta, sc_sh);
    k_affine      <<<2048, 256, 0, stream>>>(H, sc_sh);
    k_convertA    <<<2048, 256, 0, stream>>>(A, Ab);
    k_aat         <<<2048, 256, 0, stream>>>(Ab, B2);
    k_gemm3<false><<<1024, 256, 0, stream>>>(B2, H, nullptr, x, eps_p, out);
  }
  k_at<<<dim3(8, 8, 128), 256, 0, stream>>>(A, At);
}

// Round 9
// 296.491 us; speedup vs baseline: 1.0938x; 1.0938x over previous
//
#include <hip/hip_runtime.h>
#include <stdint.h>

// ---------- types ----------
typedef __bf16 bf16x8 __attribute__((ext_vector_type(8)));
typedef float f32x4 __attribute__((ext_vector_type(4)));
typedef unsigned short us8_t __attribute__((ext_vector_type(8)));

#define LDSK 40  // padded row for reg-staged B tile in gemm3

__device__ __forceinline__ unsigned short f2bf(float f) {
  __bf16 b = (__bf16)f;
  return __builtin_bit_cast(unsigned short, b);
}
__device__ __forceinline__ float bf2f(unsigned short u) {
  union { uint32_t u; float f; } v; v.u = ((uint32_t)u) << 16;
  return v.f;
}

// async global->LDS, 16B per lane (wave-uniform LDS base + lane*16)
__device__ __forceinline__ void gload16(const void* g, void* l) {
  __builtin_amdgcn_global_load_lds(
      (const __attribute__((address_space(1))) void*)g,
      (__attribute__((address_space(3))) void*)l, 16, 0, 0);
}

// Stage a 128x32-short bf16 tile (linear [128][32] LDS) via 2 gload16/wave.
__device__ __forceinline__ void stage_tile(const unsigned short* g, size_t ldg,
                                           unsigned short* lds, int wid, int lane) {
#pragma unroll
  for (int i = 0; i < 2; ++i) {
    int seg = wid * 2 + i;  // 0..7, 16 rows each
    const unsigned short* gp = g + (size_t)(seg * 16 + (lane >> 2)) * ldg + (lane & 3) * 8;
    gload16(gp, lds + seg * 512);
  }
}

// 16 MFMA on a staged tile pair. A stride fixed 32 shorts; B stride param.
__device__ __forceinline__ void mfma_step(const unsigned short* As, const unsigned short* Bs,
                                          int ldb, f32x4 (*acc)[4],
                                          int wr, int wc, int lr, int lk) {
  bf16x8 a[4], b[4];
#pragma unroll
  for (int mi = 0; mi < 4; ++mi)
    a[mi] = *(const bf16x8*)(As + (wr + mi * 16 + lr) * 32 + lk * 8);
#pragma unroll
  for (int ni = 0; ni < 4; ++ni)
    b[ni] = *(const bf16x8*)(Bs + (wc + ni * 16 + lr) * ldb + lk * 8);
#pragma unroll
  for (int mi = 0; mi < 4; ++mi)
#pragma unroll
    for (int ni = 0; ni < 4; ++ni)
      acc[mi][ni] = __builtin_amdgcn_mfma_f32_16x16x32_bf16(a[mi], b[ni], acc[mi][ni], 0, 0, 0);
}

// =====================================================================
// Convert x (16.7M f32) and W (0.52M f32) to bf16 (into out region).
// =====================================================================
__global__ __launch_bounds__(256) void k_convert(
    const float* __restrict__ X, const float* __restrict__ W,
    unsigned short* __restrict__ Xb, unsigned short* __restrict__ Wb) {
  const size_t idx = (size_t)blockIdx.x * 256 + threadIdx.x;
  const size_t stride = (size_t)gridDim.x * 256;
  for (size_t i = idx; i < (size_t)16777216 / 8; i += stride) {
    float4 f0 = ((const float4*)X)[2 * i], f1 = ((const float4*)X)[2 * i + 1];
    us8_t w = { f2bf(f0.x), f2bf(f0.y), f2bf(f0.z), f2bf(f0.w),
                f2bf(f1.x), f2bf(f1.y), f2bf(f1.z), f2bf(f1.w) };
    ((us8_t*)Xb)[i] = w;
  }
  for (size_t i = idx; i < (size_t)524288 / 8; i += stride) {
    float4 f0 = ((const float4*)W)[2 * i], f1 = ((const float4*)W)[2 * i + 1];
    us8_t w = { f2bf(f0.x), f2bf(f0.y), f2bf(f0.z), f2bf(f0.w),
                f2bf(f1.x), f2bf(f1.y), f2bf(f1.z), f2bf(f1.w) };
    ((us8_t*)Wb)[i] = w;
  }
}

// =====================================================================
// Stage 1: h[n,o,v] = sum_c W[o,c]*x[n,v,c] + b[o]  (bf16 out, raw h)
// 1-phase bf16 gload_lds (proven fastest structure for this size).
// =====================================================================
__global__ __launch_bounds__(256) void k_gemm1(
    const unsigned short* __restrict__ Wb, const unsigned short* __restrict__ Xb,
    const float* __restrict__ convb, unsigned short* __restrict__ H) {
  __shared__ unsigned short As[4096];
  __shared__ unsigned short Bs[4096];
  const int tid = threadIdx.x;
  const int L = blockIdx.x;
  const int xcd = L & 7, slot = L >> 3;
  const int n = xcd * 8 + (slot >> 5);
  const int tile = slot & 31;
  const int tm = tile >> 2, tn = tile & 3;
  const unsigned short* gA = Wb + (size_t)tm * 128 * 512;
  const unsigned short* gB = Xb + ((size_t)n * 512 + tn * 128) * 512;
  const int lane = tid & 63, wid = tid >> 6;
  const int wr = (wid >> 1) * 64, wc = (wid & 1) * 64;
  const int lr = lane & 15, lk = lane >> 4;
  f32x4 acc[4][4] = {};
  for (int k0 = 0; k0 < 512; k0 += 32) {
    stage_tile(gA + k0, 512, As, wid, lane);
    stage_tile(gB + k0, 512, Bs, wid, lane);
    __syncthreads();
    mfma_step(As, Bs, 32, acc, wr, wc, lr, lk);
    __syncthreads();
  }
  unsigned short* Hn = H + (size_t)n * 1024 * 512;
#pragma unroll
  for (int mi = 0; mi < 4; ++mi)
#pragma unroll
    for (int i = 0; i < 4; ++i) {
      int o = tm * 128 + wr + mi * 16 + lk * 4 + i;
      float bias = convb[o];
#pragma unroll
      for (int ni = 0; ni < 4; ++ni) {
        int v = tn * 128 + wc + ni * 16 + lr;
        Hn[(size_t)o * 512 + v] = f2bf(acc[mi][ni][i] + bias);
      }
    }
}

// =====================================================================
// Fused: BN stats (blocks 0..1023) + convert A->Ab bf16 (blocks 1024+).
// Independent work; overlaps bn's half-chip grid with convertA BW.
// =====================================================================
__global__ __launch_bounds__(256) void k_bn_convA(
    const unsigned short* __restrict__ H, const float* __restrict__ gamma,
    const float* __restrict__ beta, float* __restrict__ sc_sh,
    const float* __restrict__ A, unsigned short* __restrict__ Ab) {
  const int tid = threadIdx.x;
  if (blockIdx.x < 1024) {
    const int o = blockIdx.x;
    const int g = tid >> 6, l = tid & 63;
    float s1 = 0.f, s2 = 0.f;
    for (int step = 0; step < 16; ++step) {
      int n = g + step * 4;
      const us8_t* row = (const us8_t*)(H + ((size_t)n * 1024 + o) * 512);
      us8_t v = row[l];
#pragma unroll
      for (int j = 0; j < 8; ++j) { float f = bf2f(v[j]); s1 += f; s2 += f * f; }
    }
    __shared__ float r1[256], r2[256];
    r1[tid] = s1; r2[tid] = s2;
    __syncthreads();
    for (int off = 128; off > 0; off >>= 1) {
      if (tid < off) { r1[tid] += r1[tid + off]; r2[tid] += r2[tid + off]; }
      __syncthreads();
    }
    if (tid == 0) {
      float mean = r1[0] * (1.0f / 32768.0f);
      float var = r2[0] * (1.0f / 32768.0f) - mean * mean;
      float s = gamma[o] * rsqrtf(var + 1e-5f);
      sc_sh[o] = s;
      sc_sh[1024 + o] = beta[o] - mean * s;
    }
  } else {
    const size_t idx = (size_t)(blockIdx.x - 1024) * 256 + tid;
    const size_t stride = (size_t)2048 * 256;
    for (size_t i = idx; i < (size_t)33554432 / 8; i += stride) {
      float4 f0 = ((const float4*)A)[2 * i], f1 = ((const float4*)A)[2 * i + 1];
      us8_t w = { f2bf(f0.x), f2bf(f0.y), f2bf(f0.z), f2bf(f0.w),
                  f2bf(f1.x), f2bf(f1.y), f2bf(f1.z), f2bf(f1.w) };
      ((us8_t*)Ab)[i] = w;
    }
  }
}

// ---- standalone fallbacks (tiny-ws tier) ----
__global__ __launch_bounds__(256) void k_bn(
    const unsigned short* __restrict__ H, const float* __restrict__ gamma,
    const float* __restrict__ beta, float* __restrict__ sc_sh) {
  const int o = blockIdx.x;
  const int tid = threadIdx.x;
  const int g = tid >> 6, l = tid & 63;
  float s1 = 0.f, s2 = 0.f;
  for (int step = 0; step < 16; ++step) {
    int n = g + step * 4;
    const us8_t* row = (const us8_t*)(H + ((size_t)n * 1024 + o) * 512);
    us8_t v = row[l];
#pragma unroll
    for (int j = 0; j < 8; ++j) { float f = bf2f(v[j]); s1 += f; s2 += f * f; }
  }
  __shared__ float r1[256], r2[256];
  r1[tid] = s1; r2[tid] = s2;
  __syncthreads();
  for (int off = 128; off > 0; off >>= 1) {
    if (tid < off) { r1[tid] += r1[tid + off]; r2[tid] += r2[tid + off]; }
    __syncthreads();
  }
  if (tid == 0) {
    float mean = r1[0] * (1.0f / 32768.0f);
    float var = r2[0] * (1.0f / 32768.0f) - mean * mean;
    float s = gamma[o] * rsqrtf(var + 1e-5f);
    sc_sh[o] = s;
    sc_sh[1024 + o] = beta[o] - mean * s;
  }
}

__global__ __launch_bounds__(256) void k_convertA(
    const float* __restrict__ A, unsigned short* __restrict__ Ab) {
  const size_t idx = (size_t)blockIdx.x * 256 + threadIdx.x;
  const size_t stride = (size_t)gridDim.x * 256;
  for (size_t i = idx; i < (size_t)33554432 / 8; i += stride) {
    float4 f0 = ((const float4*)A)[2 * i], f1 = ((const float4*)A)[2 * i + 1];
    us8_t w = { f2bf(f0.x), f2bf(f0.y), f2bf(f0.z), f2bf(f0.w),
                f2bf(f1.x), f2bf(f1.y), f2bf(f1.z), f2bf(f1.w) };
    ((us8_t*)Ab)[i] = w;
  }
}

__global__ __launch_bounds__(256) void k_affine(
    unsigned short* __restrict__ H, const float* __restrict__ sc_sh) {
  const size_t idx = (size_t)blockIdx.x * 256 + threadIdx.x;
  const size_t stride = (size_t)gridDim.x * 256;
  const size_t total8 = (size_t)64 * 1024 * 512 / 8;
  for (size_t i = idx; i < total8; i += stride) {
    size_t base = i * 8;
    int o = (int)((base >> 9) & 1023);
    float sc = sc_sh[o], sh = sc_sh[1024 + o];
    us8_t v = ((const us8_t*)H)[i];
    us8_t w;
#pragma unroll
    for (int j = 0; j < 8; ++j) w[j] = f2bf(fmaf(bf2f(v[j]), sc, sh));
    ((us8_t*)H)[i] = w;
  }
}

// =====================================================================
// Stage 2': B2[nk][m,m'] = sum_e Ab[m,e]*Ab[m',e]  (1-phase bf16)
// =====================================================================
__global__ __launch_bounds__(256) void k_aat(
    const unsigned short* __restrict__ Ab, unsigned short* __restrict__ B2) {
  __shared__ unsigned short As[4096];
  __shared__ unsigned short Bs[4096];
  const int tid = threadIdx.x;
  const int L = blockIdx.x;
  const int xcd = L & 7, slot = L >> 3;
  const int nk = xcd * 16 + (slot >> 4);
  const int tile = slot & 15;
  const int tm = tile >> 2, tn = tile & 3;
  const unsigned short* Ank = Ab + (size_t)nk * 262144;
  const unsigned short* gA = Ank + (size_t)tm * 128 * 512;
  const unsigned short* gB = Ank + (size_t)tn * 128 * 512;
  const int lane = tid & 63, wid = tid >> 6;
  const int wr = (wid >> 1) * 64, wc = (wid & 1) * 64;
  const int lr = lane & 15, lk = lane >> 4;
  f32x4 acc[4][4] = {};
  for (int k0 = 0; k0 < 512; k0 += 32) {
    stage_tile(gA + k0, 512, As, wid, lane);
    stage_tile(gB + k0, 512, Bs, wid, lane);
    __syncthreads();
    mfma_step(As, Bs, 32, acc, wr, wc, lr, lk);
    __syncthreads();
  }
  unsigned short* Bn = B2 + (size_t)nk * 262144;
#pragma unroll
  for (int mi = 0; mi < 4; ++mi)
#pragma unroll
    for (int i = 0; i < 4; ++i) {
      int m = tm * 128 + wr + mi * 16 + lk * 4 + i;
#pragma unroll
      for (int ni = 0; ni < 4; ++ni) {
        int mp = tn * 128 + wc + ni * 16 + lr;
        Bn[(size_t)m * 512 + mp] = f2bf(acc[mi][ni][i]);
      }
    }
}

// =====================================================================
// Stage 3': out[n,v,c] = (1+eps)*x + sum_kk sum_m' B2[nk][v,m'] * h'[o,m']
// A-op via gload_lds; B-op reg-staged with BN affine folded (proven form).
// =====================================================================
template <bool AFFINE>
__global__ __launch_bounds__(256) void k_gemm3(
    const unsigned short* __restrict__ B2, const unsigned short* __restrict__ H,
    const float* __restrict__ sc_sh, const float* __restrict__ X,
    const float* __restrict__ epsp, float* __restrict__ out) {
  __shared__ unsigned short As[4096];               // linear: gload_lds dest
  __shared__ unsigned short Bs[128 * LDSK];         // padded: reg-staged
  __shared__ float s_sc[2][128], s_sh[2][128];
  const int tid = threadIdx.x;
  const int L = blockIdx.x;
  const int xcd = L & 7, slot = L >> 3;
  const int n = xcd * 8 + (slot >> 4);
  const int tile = slot & 15;
  const int tm = tile >> 2, tn = tile & 3;
  const int lane = tid & 63, wid = tid >> 6;
  const int wr = (wid >> 1) * 64, wc = (wid & 1) * 64;
  const int lr = lane & 15, lk = lane >> 4;
  if (AFFINE) {
    if (tid < 256) {
      int kkq = tid >> 7, r = tid & 127;
      s_sc[kkq][r] = sc_sh[kkq * 512 + tn * 128 + r];
      s_sh[kkq][r] = sc_sh[1024 + kkq * 512 + tn * 128 + r];
    }
    __syncthreads();
  }
  f32x4 acc[4][4] = {};
  for (int kk = 0; kk < 2; ++kk) {
    const unsigned short* gA = B2 + ((size_t)(n * 2 + kk) * 512 + tm * 128) * 512;
    const unsigned short* gB = H + ((size_t)n * 1024 + kk * 512 + tn * 128) * 512;
    for (int k0 = 0; k0 < 512; k0 += 32) {
      stage_tile(gA + k0, 512, As, wid, lane);  // async, overlaps Bs staging
#pragma unroll
      for (int i = 0; i < 2; ++i) {
        int s = tid + i * 256;
        int r = s >> 2, c8 = (s & 3) * 8;
        us8_t v = *(const us8_t*)(gB + (size_t)r * 512 + k0 + c8);
        if (AFFINE) {
          float sc = s_sc[kk][r], sh = s_sh[kk][r];
          us8_t w;
#pragma unroll
          for (int j = 0; j < 8; ++j) w[j] = f2bf(fmaf(bf2f(v[j]), sc, sh));
          *(us8_t*)&Bs[r * LDSK + c8] = w;
        } else {
          *(us8_t*)&Bs[r * LDSK + c8] = v;
        }
      }
      __syncthreads();
      mfma_step(As, Bs, LDSK, acc, wr, wc, lr, lk);
      __syncthreads();
    }
  }
  const float e1 = 1.0f + epsp[0];
#pragma unroll
  for (int mi = 0; mi < 4; ++mi)
#pragma unroll
    for (int i = 0; i < 4; ++i) {
      int v = tm * 128 + wr + mi * 16 + lk * 4 + i;
#pragma unroll
      for (int ni = 0; ni < 4; ++ni) {
        int c = tn * 128 + wc + ni * 16 + lr;
        size_t idx = ((size_t)n * 512 + v) * 512 + c;
        out[idx] = fmaf(e1, X[idx], acc[mi][ni][i]);
      }
    }
}

// =====================================================================
// At[nk,e,m] = A[nk,m,e]  (runs LAST) — 64x64 float4 tiles
// =====================================================================
__global__ __launch_bounds__(256) void k_at(
    const float* __restrict__ A, float* __restrict__ At) {
  __shared__ float tile[64][65];
  const int nk = blockIdx.z;
  const int e0 = blockIdx.x * 64, m0 = blockIdx.y * 64;
  const float* src = A + (size_t)nk * 262144;
  float* dst = At + (size_t)nk * 262144;
  const int t = threadIdx.x;
#pragma unroll
  for (int j = 0; j < 4; ++j) {
    int ch = t + j * 256;
    int r = ch >> 4, c4 = (ch & 15) * 4;
    float4 f = *(const float4*)(src + (size_t)(m0 + r) * 512 + e0 + c4);
    tile[r][c4] = f.x; tile[r][c4 + 1] = f.y; tile[r][c4 + 2] = f.z; tile[r][c4 + 3] = f.w;
  }
  __syncthreads();
#pragma unroll
  for (int j = 0; j < 4; ++j) {
    int ch = t + j * 256;
    int e = ch >> 4, m4 = (ch & 15) * 4;
    float4 g = { tile[m4][e], tile[m4 + 1][e], tile[m4 + 2][e], tile[m4 + 3][e] };
    *(float4*)(dst + (size_t)(e0 + e) * 512 + m0 + m4) = g;
  }
}

// =====================================================================
extern "C" void kernel_launch(void* const* d_in, const int* in_sizes, int n_in,
                              void* d_out, int out_size, void* d_ws, size_t ws_size,
                              hipStream_t stream) {
  const float* x      = (const float*)d_in[0];  // (64,512,512)
  const float* A      = (const float*)d_in[1];  // (64,2,512,512)
  const float* conv_w = (const float*)d_in[2];  // (1024,512)
  const float* conv_b = (const float*)d_in[3];  // (1024,)
  const float* gamma  = (const float*)d_in[4];  // (1024,)
  const float* beta   = (const float*)d_in[5];  // (1024,)
  const float* eps_p  = (const float*)d_in[6];  // (1,)

  float* out = (float*)d_out;           // 16,777,216 floats (67 MB)
  float* At  = out + (size_t)16777216;  // 33,554,432 floats (134 MB)

  // Scratch (inside d_out; every byte dead before its region's final write):
  //   At region: B2 bf16 [0..33.5M shorts) | H bf16 [33.5M..67M shorts)
  //   out region timeline: {Xb|Wb} -> (gemm1 consumes) -> {Ab} -> (gemm3 overwrites)
  unsigned short* B2 = (unsigned short*)At;
  unsigned short* H  = (unsigned short*)(At + (size_t)16777216);
  unsigned short* Xb = (unsigned short*)out;
  unsigned short* Wb = Xb + (size_t)16777216;
  unsigned short* Ab = (unsigned short*)out;  // 33.5M shorts = exact out-region fit

  float* wsf = (float*)d_ws;

  if (ws_size >= 8192) {
    float* sc_sh = wsf;
    k_convert    <<<2048, 256, 0, stream>>>(x, conv_w, Xb, Wb);
    k_gemm1      <<<2048, 256, 0, stream>>>(Wb, Xb, conv_b, H);
    k_bn_convA   <<<3072, 256, 0, stream>>>(H, gamma, beta, sc_sh, A, Ab);
    k_aat        <<<2048, 256, 0, stream>>>(Ab, B2);
    k_gemm3<true><<<1024, 256, 0, stream>>>(B2, H, sc_sh, x, eps_p, out);
  } else {
    // sc_sh in dead Xb space; affine applied before convertA overwrites it.
    float* sc_sh = out;
    k_convert     <<<2048, 256, 0, stream>>>(x, conv_w, Xb, Wb);
    k_gemm1       <<<2048, 256, 0, stream>>>(Wb, Xb, conv_b, H);
    k_bn          <<<1024, 256, 0, stream>>>(H, gamma, beta, sc_sh);
    k_affine      <<<2048, 256, 0, stream>>>(H, sc_sh);
    k_convertA    <<<2048, 256, 0, stream>>>(A, Ab);
    k_aat         <<<2048, 256, 0, stream>>>(Ab, B2);
    k_gemm3<false><<<1024, 256, 0, stream>>>(B2, H, nullptr, x, eps_p, out);
  }
  k_at<<<dim3(8, 8, 128), 256, 0, stream>>>(A, At);
}

// Round 10
// 276.734 us; speedup vs baseline: 1.1719x; 1.0714x over previous
//
#include <hip/hip_runtime.h>
#include <stdint.h>

// ---------- types ----------
typedef __bf16 bf16x8 __attribute__((ext_vector_type(8)));
typedef float f32x4 __attribute__((ext_vector_type(4)));
typedef unsigned short us4_t __attribute__((ext_vector_type(4)));
typedef unsigned short us8_t __attribute__((ext_vector_type(8)));

#define LDSK 40  // padded row for reg-staged B tile in gemm3

__device__ __forceinline__ unsigned short f2bf(float f) {
  __bf16 b = (__bf16)f;
  return __builtin_bit_cast(unsigned short, b);
}
__device__ __forceinline__ float bf2f(unsigned short u) {
  union { uint32_t u; float f; } v; v.u = ((uint32_t)u) << 16;
  return v.f;
}

// async global->LDS, 16B per lane (wave-uniform LDS base + lane*16)
__device__ __forceinline__ void gload16(const void* g, void* l) {
  __builtin_amdgcn_global_load_lds(
      (const __attribute__((address_space(1))) void*)g,
      (__attribute__((address_space(3))) void*)l, 16, 0, 0);
}

// Stage a 128x32-short bf16 tile (linear [128][32] LDS) via 2 gload16/wave.
__device__ __forceinline__ void stage_tile(const unsigned short* g, size_t ldg,
                                           unsigned short* lds, int wid, int lane) {
#pragma unroll
  for (int i = 0; i < 2; ++i) {
    int seg = wid * 2 + i;  // 0..7, 16 rows each
    const unsigned short* gp = g + (size_t)(seg * 16 + (lane >> 2)) * ldg + (lane & 3) * 8;
    gload16(gp, lds + seg * 512);
  }
}

// 16 MFMA on a staged tile pair. A stride fixed 32 shorts; B stride param.
__device__ __forceinline__ void mfma_step(const unsigned short* As, const unsigned short* Bs,
                                          int ldb, f32x4 (*acc)[4],
                                          int wr, int wc, int lr, int lk) {
  bf16x8 a[4], b[4];
#pragma unroll
  for (int mi = 0; mi < 4; ++mi)
    a[mi] = *(const bf16x8*)(As + (wr + mi * 16 + lr) * 32 + lk * 8);
#pragma unroll
  for (int ni = 0; ni < 4; ++ni)
    b[ni] = *(const bf16x8*)(Bs + (wc + ni * 16 + lr) * ldb + lk * 8);
#pragma unroll
  for (int mi = 0; mi < 4; ++mi)
#pragma unroll
    for (int ni = 0; ni < 4; ++ni)
      acc[mi][ni] = __builtin_amdgcn_mfma_f32_16x16x32_bf16(a[mi], b[ni], acc[mi][ni], 0, 0, 0);
}

// =====================================================================
// Convert x (16.7M f32) and W (0.52M f32) to bf16 (into out region).
// =====================================================================
__global__ __launch_bounds__(256) void k_convert(
    const float* __restrict__ X, const float* __restrict__ W,
    unsigned short* __restrict__ Xb, unsigned short* __restrict__ Wb) {
  const size_t idx = (size_t)blockIdx.x * 256 + threadIdx.x;
  const size_t stride = (size_t)gridDim.x * 256;
  for (size_t i = idx; i < (size_t)16777216 / 8; i += stride) {
    float4 f0 = ((const float4*)X)[2 * i], f1 = ((const float4*)X)[2 * i + 1];
    us8_t w = { f2bf(f0.x), f2bf(f0.y), f2bf(f0.z), f2bf(f0.w),
                f2bf(f1.x), f2bf(f1.y), f2bf(f1.z), f2bf(f1.w) };
    ((us8_t*)Xb)[i] = w;
  }
  for (size_t i = idx; i < (size_t)524288 / 8; i += stride) {
    float4 f0 = ((const float4*)W)[2 * i], f1 = ((const float4*)W)[2 * i + 1];
    us8_t w = { f2bf(f0.x), f2bf(f0.y), f2bf(f0.z), f2bf(f0.w),
                f2bf(f1.x), f2bf(f1.y), f2bf(f1.z), f2bf(f1.w) };
    ((us8_t*)Wb)[i] = w;
  }
}

// =====================================================================
// Stage 1: h[n,o,v] = sum_c W[o,c]*x[n,v,c] + b[o]  (bf16 out, raw h)
// 1-phase bf16 gload_lds (proven fastest structure for this size).
// =====================================================================
__global__ __launch_bounds__(256) void k_gemm1(
    const unsigned short* __restrict__ Wb, const unsigned short* __restrict__ Xb,
    const float* __restrict__ convb, unsigned short* __restrict__ H) {
  __shared__ unsigned short As[4096];
  __shared__ unsigned short Bs[4096];
  const int tid = threadIdx.x;
  const int L = blockIdx.x;
  const int xcd = L & 7, slot = L >> 3;
  const int n = xcd * 8 + (slot >> 5);
  const int tile = slot & 31;
  const int tm = tile >> 2, tn = tile & 3;
  const unsigned short* gA = Wb + (size_t)tm * 128 * 512;
  const unsigned short* gB = Xb + ((size_t)n * 512 + tn * 128) * 512;
  const int lane = tid & 63, wid = tid >> 6;
  const int wr = (wid >> 1) * 64, wc = (wid & 1) * 64;
  const int lr = lane & 15, lk = lane >> 4;
  f32x4 acc[4][4] = {};
  for (int k0 = 0; k0 < 512; k0 += 32) {
    stage_tile(gA + k0, 512, As, wid, lane);
    stage_tile(gB + k0, 512, Bs, wid, lane);
    __syncthreads();
    mfma_step(As, Bs, 32, acc, wr, wc, lr, lk);
    __syncthreads();
  }
  unsigned short* Hn = H + (size_t)n * 1024 * 512;
#pragma unroll
  for (int mi = 0; mi < 4; ++mi)
#pragma unroll
    for (int i = 0; i < 4; ++i) {
      int o = tm * 128 + wr + mi * 16 + lk * 4 + i;
      float bias = convb[o];
#pragma unroll
      for (int ni = 0; ni < 4; ++ni) {
        int v = tn * 128 + wc + ni * 16 + lr;
        Hn[(size_t)o * 512 + v] = f2bf(acc[mi][ni][i] + bias);
      }
    }
}

// =====================================================================
// Fused (fast path): BN stats (blocks 0..1023) + transpose A->At with
// Ab bf16 emitted from the same read (blocks 1024..9215).
// Single read of A serves both At and Ab.
// =====================================================================
__global__ __launch_bounds__(256) void k_bn_at_ab(
    const unsigned short* __restrict__ H, const float* __restrict__ gamma,
    const float* __restrict__ beta, float* __restrict__ sc_sh,
    const float* __restrict__ A, float* __restrict__ At,
    unsigned short* __restrict__ Ab) {
  const int tid = threadIdx.x;
  if (blockIdx.x < 1024) {
    const int o = blockIdx.x;
    const int g = tid >> 6, l = tid & 63;
    float s1 = 0.f, s2 = 0.f;
    for (int step = 0; step < 16; ++step) {
      int n = g + step * 4;
      const us8_t* row = (const us8_t*)(H + ((size_t)n * 1024 + o) * 512);
      us8_t v = row[l];
#pragma unroll
      for (int j = 0; j < 8; ++j) { float f = bf2f(v[j]); s1 += f; s2 += f * f; }
    }
    __shared__ float r1[256], r2[256];
    r1[tid] = s1; r2[tid] = s2;
    __syncthreads();
    for (int off = 128; off > 0; off >>= 1) {
      if (tid < off) { r1[tid] += r1[tid + off]; r2[tid] += r2[tid + off]; }
      __syncthreads();
    }
    if (tid == 0) {
      float mean = r1[0] * (1.0f / 32768.0f);
      float var = r2[0] * (1.0f / 32768.0f) - mean * mean;
      float s = gamma[o] * rsqrtf(var + 1e-5f);
      sc_sh[o] = s;
      sc_sh[1024 + o] = beta[o] - mean * s;
    }
  } else {
    __shared__ float tile[64][65];
    const int tIdx = blockIdx.x - 1024;     // 0..8191
    const int nk = tIdx >> 6;
    const int e0 = (tIdx & 7) * 64, m0 = ((tIdx >> 3) & 7) * 64;
    const float* src = A + (size_t)nk * 262144;
    float* dst = At + (size_t)nk * 262144;
    unsigned short* ab = Ab + (size_t)nk * 262144;
#pragma unroll
    for (int j = 0; j < 4; ++j) {
      int ch = tid + j * 256;
      int r = ch >> 4, c4 = (ch & 15) * 4;
      float4 f = *(const float4*)(src + (size_t)(m0 + r) * 512 + e0 + c4);
      tile[r][c4] = f.x; tile[r][c4 + 1] = f.y; tile[r][c4 + 2] = f.z; tile[r][c4 + 3] = f.w;
      us4_t u = { f2bf(f.x), f2bf(f.y), f2bf(f.z), f2bf(f.w) };
      *(us4_t*)(ab + (size_t)(m0 + r) * 512 + e0 + c4) = u;
    }
    __syncthreads();
#pragma unroll
    for (int j = 0; j < 4; ++j) {
      int ch = tid + j * 256;
      int e = ch >> 4, m4 = (ch & 15) * 4;
      float4 g = { tile[m4][e], tile[m4 + 1][e], tile[m4 + 2][e], tile[m4 + 3][e] };
      *(float4*)(dst + (size_t)(e0 + e) * 512 + m0 + m4) = g;
    }
  }
}

// =====================================================================
// Fused (mid path): BN stats + convert A->Ab (R9 proven form).
// =====================================================================
__global__ __launch_bounds__(256) void k_bn_convA(
    const unsigned short* __restrict__ H, const float* __restrict__ gamma,
    const float* __restrict__ beta, float* __restrict__ sc_sh,
    const float* __restrict__ A, unsigned short* __restrict__ Ab) {
  const int tid = threadIdx.x;
  if (blockIdx.x < 1024) {
    const int o = blockIdx.x;
    const int g = tid >> 6, l = tid & 63;
    float s1 = 0.f, s2 = 0.f;
    for (int step = 0; step < 16; ++step) {
      int n = g + step * 4;
      const us8_t* row = (const us8_t*)(H + ((size_t)n * 1024 + o) * 512);
      us8_t v = row[l];
#pragma unroll
      for (int j = 0; j < 8; ++j) { float f = bf2f(v[j]); s1 += f; s2 += f * f; }
    }
    __shared__ float r1[256], r2[256];
    r1[tid] = s1; r2[tid] = s2;
    __syncthreads();
    for (int off = 128; off > 0; off >>= 1) {
      if (tid < off) { r1[tid] += r1[tid + off]; r2[tid] += r2[tid + off]; }
      __syncthreads();
    }
    if (tid == 0) {
      float mean = r1[0] * (1.0f / 32768.0f);
      float var = r2[0] * (1.0f / 32768.0f) - mean * mean;
      float s = gamma[o] * rsqrtf(var + 1e-5f);
      sc_sh[o] = s;
      sc_sh[1024 + o] = beta[o] - mean * s;
    }
  } else {
    const size_t idx = (size_t)(blockIdx.x - 1024) * 256 + tid;
    const size_t stride = (size_t)2048 * 256;
    for (size_t i = idx; i < (size_t)33554432 / 8; i += stride) {
      float4 f0 = ((const float4*)A)[2 * i], f1 = ((const float4*)A)[2 * i + 1];
      us8_t w = { f2bf(f0.x), f2bf(f0.y), f2bf(f0.z), f2bf(f0.w),
                  f2bf(f1.x), f2bf(f1.y), f2bf(f1.z), f2bf(f1.w) };
      ((us8_t*)Ab)[i] = w;
    }
  }
}

// ---- standalone fallbacks (tiny-ws tier) ----
__global__ __launch_bounds__(256) void k_bn(
    const unsigned short* __restrict__ H, const float* __restrict__ gamma,
    const float* __restrict__ beta, float* __restrict__ sc_sh) {
  const int o = blockIdx.x;
  const int tid = threadIdx.x;
  const int g = tid >> 6, l = tid & 63;
  float s1 = 0.f, s2 = 0.f;
  for (int step = 0; step < 16; ++step) {
    int n = g + step * 4;
    const us8_t* row = (const us8_t*)(H + ((size_t)n * 1024 + o) * 512);
    us8_t v = row[l];
#pragma unroll
    for (int j = 0; j < 8; ++j) { float f = bf2f(v[j]); s1 += f; s2 += f * f; }
  }
  __shared__ float r1[256], r2[256];
  r1[tid] = s1; r2[tid] = s2;
  __syncthreads();
  for (int off = 128; off > 0; off >>= 1) {
    if (tid < off) { r1[tid] += r1[tid + off]; r2[tid] += r2[tid + off]; }
    __syncthreads();
  }
  if (tid == 0) {
    float mean = r1[0] * (1.0f / 32768.0f);
    float var = r2[0] * (1.0f / 32768.0f) - mean * mean;
    float s = gamma[o] * rsqrtf(var + 1e-5f);
    sc_sh[o] = s;
    sc_sh[1024 + o] = beta[o] - mean * s;
  }
}

__global__ __launch_bounds__(256) void k_convertA(
    const float* __restrict__ A, unsigned short* __restrict__ Ab) {
  const size_t idx = (size_t)blockIdx.x * 256 + threadIdx.x;
  const size_t stride = (size_t)gridDim.x * 256;
  for (size_t i = idx; i < (size_t)33554432 / 8; i += stride) {
    float4 f0 = ((const float4*)A)[2 * i], f1 = ((const float4*)A)[2 * i + 1];
    us8_t w = { f2bf(f0.x), f2bf(f0.y), f2bf(f0.z), f2bf(f0.w),
                f2bf(f1.x), f2bf(f1.y), f2bf(f1.z), f2bf(f1.w) };
    ((us8_t*)Ab)[i] = w;
  }
}

__global__ __launch_bounds__(256) void k_affine(
    unsigned short* __restrict__ H, const float* __restrict__ sc_sh) {
  const size_t idx = (size_t)blockIdx.x * 256 + threadIdx.x;
  const size_t stride = (size_t)gridDim.x * 256;
  const size_t total8 = (size_t)64 * 1024 * 512 / 8;
  for (size_t i = idx; i < total8; i += stride) {
    size_t base = i * 8;
    int o = (int)((base >> 9) & 1023);
    float sc = sc_sh[o], sh = sc_sh[1024 + o];
    us8_t v = ((const us8_t*)H)[i];
    us8_t w;
#pragma unroll
    for (int j = 0; j < 8; ++j) w[j] = f2bf(fmaf(bf2f(v[j]), sc, sh));
    ((us8_t*)H)[i] = w;
  }
}

// =====================================================================
// Stage 2': B2[nk][m,m'] = sum_e Ab[m,e]*Ab[m',e]  (1-phase bf16)
// =====================================================================
__global__ __launch_bounds__(256) void k_aat(
    const unsigned short* __restrict__ Ab, unsigned short* __restrict__ B2) {
  __shared__ unsigned short As[4096];
  __shared__ unsigned short Bs[4096];
  const int tid = threadIdx.x;
  const int L = blockIdx.x;
  const int xcd = L & 7, slot = L >> 3;
  const int nk = xcd * 16 + (slot >> 4);
  const int tile = slot & 15;
  const int tm = tile >> 2, tn = tile & 3;
  const unsigned short* Ank = Ab + (size_t)nk * 262144;
  const unsigned short* gA = Ank + (size_t)tm * 128 * 512;
  const unsigned short* gB = Ank + (size_t)tn * 128 * 512;
  const int lane = tid & 63, wid = tid >> 6;
  const int wr = (wid >> 1) * 64, wc = (wid & 1) * 64;
  const int lr = lane & 15, lk = lane >> 4;
  f32x4 acc[4][4] = {};
  for (int k0 = 0; k0 < 512; k0 += 32) {
    stage_tile(gA + k0, 512, As, wid, lane);
    stage_tile(gB + k0, 512, Bs, wid, lane);
    __syncthreads();
    mfma_step(As, Bs, 32, acc, wr, wc, lr, lk);
    __syncthreads();
  }
  unsigned short* Bn = B2 + (size_t)nk * 262144;
#pragma unroll
  for (int mi = 0; mi < 4; ++mi)
#pragma unroll
    for (int i = 0; i < 4; ++i) {
      int m = tm * 128 + wr + mi * 16 + lk * 4 + i;
#pragma unroll
      for (int ni = 0; ni < 4; ++ni) {
        int mp = tn * 128 + wc + ni * 16 + lr;
        Bn[(size_t)m * 512 + mp] = f2bf(acc[mi][ni][i]);
      }
    }
}

// =====================================================================
// Stage 3': out[n,v,c] = (1+eps)*x + sum_kk sum_m' B2[nk][v,m'] * h'[o,m']
// A-op via gload_lds; B-op reg-staged with BN affine folded (proven form).
// =====================================================================
template <bool AFFINE>
__global__ __launch_bounds__(256) void k_gemm3(
    const unsigned short* __restrict__ B2, const unsigned short* __restrict__ H,
    const float* __restrict__ sc_sh, const float* __restrict__ X,
    const float* __restrict__ epsp, float* __restrict__ out) {
  __shared__ unsigned short As[4096];               // linear: gload_lds dest
  __shared__ unsigned short Bs[128 * LDSK];         // padded: reg-staged
  __shared__ float s_sc[2][128], s_sh[2][128];
  const int tid = threadIdx.x;
  const int L = blockIdx.x;
  const int xcd = L & 7, slot = L >> 3;
  const int n = xcd * 8 + (slot >> 4);
  const int tile = slot & 15;
  const int tm = tile >> 2, tn = tile & 3;
  const int lane = tid & 63, wid = tid >> 6;
  const int wr = (wid >> 1) * 64, wc = (wid & 1) * 64;
  const int lr = lane & 15, lk = lane >> 4;
  if (AFFINE) {
    if (tid < 256) {
      int kkq = tid >> 7, r = tid & 127;
      s_sc[kkq][r] = sc_sh[kkq * 512 + tn * 128 + r];
      s_sh[kkq][r] = sc_sh[1024 + kkq * 512 + tn * 128 + r];
    }
    __syncthreads();
  }
  f32x4 acc[4][4] = {};
  for (int kk = 0; kk < 2; ++kk) {
    const unsigned short* gA = B2 + ((size_t)(n * 2 + kk) * 512 + tm * 128) * 512;
    const unsigned short* gB = H + ((size_t)n * 1024 + kk * 512 + tn * 128) * 512;
    for (int k0 = 0; k0 < 512; k0 += 32) {
      stage_tile(gA + k0, 512, As, wid, lane);  // async, overlaps Bs staging
#pragma unroll
      for (int i = 0; i < 2; ++i) {
        int s = tid + i * 256;
        int r = s >> 2, c8 = (s & 3) * 8;
        us8_t v = *(const us8_t*)(gB + (size_t)r * 512 + k0 + c8);
        if (AFFINE) {
          float sc = s_sc[kk][r], sh = s_sh[kk][r];
          us8_t w;
#pragma unroll
          for (int j = 0; j < 8; ++j) w[j] = f2bf(fmaf(bf2f(v[j]), sc, sh));
          *(us8_t*)&Bs[r * LDSK + c8] = w;
        } else {
          *(us8_t*)&Bs[r * LDSK + c8] = v;
        }
      }
      __syncthreads();
      mfma_step(As, Bs, LDSK, acc, wr, wc, lr, lk);
      __syncthreads();
    }
  }
  const float e1 = 1.0f + epsp[0];
#pragma unroll
  for (int mi = 0; mi < 4; ++mi)
#pragma unroll
    for (int i = 0; i < 4; ++i) {
      int v = tm * 128 + wr + mi * 16 + lk * 4 + i;
#pragma unroll
      for (int ni = 0; ni < 4; ++ni) {
        int c = tn * 128 + wc + ni * 16 + lr;
        size_t idx = ((size_t)n * 512 + v) * 512 + c;
        out[idx] = fmaf(e1, X[idx], acc[mi][ni][i]);
      }
    }
}

// =====================================================================
// At[nk,e,m] = A[nk,m,e]  (fallback tiers; runs LAST) — 64x64 float4 tiles
// =====================================================================
__global__ __launch_bounds__(256) void k_at(
    const float* __restrict__ A, float* __restrict__ At) {
  __shared__ float tile[64][65];
  const int nk = blockIdx.z;
  const int e0 = blockIdx.x * 64, m0 = blockIdx.y * 64;
  const float* src = A + (size_t)nk * 262144;
  float* dst = At + (size_t)nk * 262144;
  const int t = threadIdx.x;
#pragma unroll
  for (int j = 0; j < 4; ++j) {
    int ch = t + j * 256;
    int r = ch >> 4, c4 = (ch & 15) * 4;
    float4 f = *(const float4*)(src + (size_t)(m0 + r) * 512 + e0 + c4);
    tile[r][c4] = f.x; tile[r][c4 + 1] = f.y; tile[r][c4 + 2] = f.z; tile[r][c4 + 3] = f.w;
  }
  __syncthreads();
#pragma unroll
  for (int j = 0; j < 4; ++j) {
    int ch = t + j * 256;
    int e = ch >> 4, m4 = (ch & 15) * 4;
    float4 g = { tile[m4][e], tile[m4 + 1][e], tile[m4 + 2][e], tile[m4 + 3][e] };
    *(float4*)(dst + (size_t)(e0 + e) * 512 + m0 + m4) = g;
  }
}

// =====================================================================
extern "C" void kernel_launch(void* const* d_in, const int* in_sizes, int n_in,
                              void* d_out, int out_size, void* d_ws, size_t ws_size,
                              hipStream_t stream) {
  const float* x      = (const float*)d_in[0];  // (64,512,512)
  const float* A      = (const float*)d_in[1];  // (64,2,512,512)
  const float* conv_w = (const float*)d_in[2];  // (1024,512)
  const float* conv_b = (const float*)d_in[3];  // (1024,)
  const float* gamma  = (const float*)d_in[4];  // (1024,)
  const float* beta   = (const float*)d_in[5];  // (1024,)
  const float* eps_p  = (const float*)d_in[6];  // (1,)

  float* out = (float*)d_out;           // 16,777,216 floats (67 MB)
  float* At  = out + (size_t)16777216;  // 33,554,432 floats (134 MB)

  unsigned short* Xb = (unsigned short*)out;
  unsigned short* Wb = Xb + (size_t)16777216;
  unsigned short* Ab = (unsigned short*)out;  // overwrites Xb/Wb after gemm1

  // Fast path: H + B2 + sc_sh in d_ws -> At region never used as scratch,
  // so transpose runs mid-pipeline fused with Ab conversion (A read ONCE).
  const size_t WS_BIG = (size_t)2 * 67108864 + 8192;
  if (ws_size >= WS_BIG) {
    unsigned short* H  = (unsigned short*)d_ws;                    // 33.5M shorts
    unsigned short* B2 = H + (size_t)33554432;                     // 33.5M shorts
    float* sc_sh = (float*)(B2 + (size_t)33554432);                // 2048 f32
    k_convert    <<<2048, 256, 0, stream>>>(x, conv_w, Xb, Wb);
    k_gemm1      <<<2048, 256, 0, stream>>>(Wb, Xb, conv_b, H);
    k_bn_at_ab   <<<9216, 256, 0, stream>>>(H, gamma, beta, sc_sh, A, At, Ab);
    k_aat        <<<2048, 256, 0, stream>>>(Ab, B2);
    k_gemm3<true><<<1024, 256, 0, stream>>>(B2, H, sc_sh, x, eps_p, out);
    return;
  }

  // Mid path (R9-proven): scratch inside d_out, sc_sh in small ws.
  unsigned short* B2 = (unsigned short*)At;
  unsigned short* H  = (unsigned short*)(At + (size_t)16777216);
  float* wsf = (float*)d_ws;

  if (ws_size >= 8192) {
    float* sc_sh = wsf;
    k_convert    <<<2048, 256, 0, stream>>>(x, conv_w, Xb, Wb);
    k_gemm1      <<<2048, 256, 0, stream>>>(Wb, Xb, conv_b, H);
    k_bn_convA   <<<3072, 256, 0, stream>>>(H, gamma, beta, sc_sh, A, Ab);
    k_aat        <<<2048, 256, 0, stream>>>(Ab, B2);
    k_gemm3<true><<<1024, 256, 0, stream>>>(B2, H, sc_sh, x, eps_p, out);
  } else {
    // sc_sh in dead Xb space; affine applied before convertA overwrites it.
    float* sc_sh = out;
    k_convert     <<<2048, 256, 0, stream>>>(x, conv_w, Xb, Wb);
    k_gemm1       <<<2048, 256, 0, stream>>>(Wb, Xb, conv_b, H);
    k_bn          <<<1024, 256, 0, stream>>>(H, gamma, beta, sc_sh);
    k_affine      <<<2048, 256, 0, stream>>>(H, sc_sh);
    k_convertA    <<<2048, 256, 0, stream>>>(A, Ab);
    k_aat         <<<2048, 256, 0, stream>>>(Ab, B2);
    k_gemm3<false><<<1024, 256, 0, stream>>>(B2, H, nullptr, x, eps_p, out);
  }
  k_at<<<dim3(8, 8, 128), 256, 0, stream>>>(A, At);
}